// Round 13
// baseline (963.186 us; speedup 1.0000x reference)
//
#include <hip/hip_runtime.h>
#include <cstdint>

// B=16, C=64, H=W=256. 3x3 convs via bf16 MFMA implicit GEMM.
// Round 13: round-10's weights-in-LDS pure-LDS compute cluster (the proven
// 124us/conv core) + occupancy fix: 1024-thread blocks (16 waves = 4 rows x
// 4 pixel-quarters -> 4 waves/SIMD), 6-row pixel chunks, chunk-sliced
// double-buffered weight tiles (2x20KB). LDS 143360B, VMCNT(6) counted waits.
using short8  = __attribute__((ext_vector_type(8))) short;
using short4v = __attribute__((ext_vector_type(4))) short;
using f32x16  = __attribute__((ext_vector_type(16))) float;
using float4v = __attribute__((ext_vector_type(4))) float;
typedef unsigned short ushort_t;

#define XROW 520            // slots per staged input row (65 mg x 8)
#define XCH 3120            // 6 rows per chunk
#define XBUF 3200           // padded slot count (stripes overrun to 3195)
#define XSH (XBUF * 8)      // shorts per pixel buffer = 25600
#define WSHB (20 * 512)     // shorts per weight buffer (18 rows + 2 pad)
#define WB0 0
#define WB1 WSHB
#define XB0 (2 * WSHB)
#define XB1 (2 * WSHB + XSH)
#define DYN_LDS ((2 * WSHB + 2 * XSH) * 2)  // 143360 B

__device__ __forceinline__ float lrelu(float x) { return x > 0.f ? x : 0.1f * x; }

__device__ __forceinline__ ushort_t f2bf(float f) {
    union { float f; unsigned u; } v; v.f = f;
    unsigned r = (v.u + 0x7FFFu + ((v.u >> 16) & 1u)) >> 16;
    return (ushort_t)r;
}
__device__ __forceinline__ float bf2f(ushort_t b) {
    union { unsigned u; float f; } v; v.u = ((unsigned)b) << 16; return v.f;
}

// async 16B global -> LDS (dest = wave-uniform base; HW adds lane*16)
__device__ __forceinline__ void gload_lds16(const ushort_t* g, ushort_t* l) {
    __builtin_amdgcn_global_load_lds(
        (const __attribute__((address_space(1))) void*)g,
        (__attribute__((address_space(3))) void*)l, 16, 0, 0);
}

#define VMCNT(n) asm volatile("s_waitcnt vmcnt(" #n ")" ::: "memory")
#define RBAR() __builtin_amdgcn_s_barrier()
#define SCHED0() __builtin_amdgcn_sched_barrier(0)

// ---------------------------------------------------------------------------
// Tiny branch: ktr[b][tap][c] = leaky(kern) * sigmoid-gate (mv folded in).
// ---------------------------------------------------------------------------
__global__ void k_tiny(const float* __restrict__ t, const float* __restrict__ tW1,
                       const float* __restrict__ tW2, const float* __restrict__ kW1,
                       const float* __restrict__ kW2, float* __restrict__ ktr) {
    int b = blockIdx.x;
    int c = threadIdx.x;  // 64
    __shared__ float h1[64], g1[64];
    float ts = t[b];
    h1[c] = lrelu(ts * tW1[c]);
    g1[c] = lrelu(ts * kW1[c]);
    __syncthreads();
    float s = 0.f;
    for (int j = 0; j < 64; ++j) s = fmaf(tW2[c * 64 + j], h1[j], s);
    float mvv = 1.f / (1.f + expf(-s));
    for (int q = 0; q < 9; ++q) {
        float s2 = 0.f;
        for (int j = 0; j < 64; ++j) s2 = fmaf(kW2[(c * 9 + q) * 64 + j], g1[j], s2);
        ktr[b * 576 + q * 64 + c] = lrelu(s2) * mvv;
    }
}

// ---------------------------------------------------------------------------
// Zero row buffer (edge-redirect source for staging).
// ---------------------------------------------------------------------------
__global__ void k_zrow(ushort_t* __restrict__ z) {
    int i = blockIdx.x * 256 + threadIdx.x;  // 2048 threads, 16384 shorts
    *(short8*)(z + (size_t)i * 8) = (short8)0;
}

// ---------------------------------------------------------------------------
// Pack three 64x64x3x3 weight tensors into MFMA A-fragment order (bf16).
// flat = ((t*4 + chunk)*2 + ct)*512 + lane*8 + j
//   = W[co = ct*32 + (lane&31)][ci = chunk*16 + (lane>>5)*8 + j], tap t
// ---------------------------------------------------------------------------
__global__ void k_pack(const float* __restrict__ w1, const float* __restrict__ w2,
                       const float* __restrict__ w3, ushort_t* __restrict__ wp) {
    int idx = blockIdx.x * 256 + threadIdx.x;
    if (idx >= 3 * 36864) return;
    int conv = idx / 36864, r = idx % 36864;
    const float* W = conv == 0 ? w1 : (conv == 1 ? w2 : w3);
    int j = r & 7, lane = (r >> 3) & 63, ct = (r >> 9) & 1, chunk = (r >> 10) & 3,
        t = r >> 12;
    int co = ct * 32 + (lane & 31);
    int ci = chunk * 16 + (lane >> 5) * 8 + j;
    wp[idx] = f2bf(W[(co * 64 + ci) * 9 + t]);
}

// ---------------------------------------------------------------------------
// Transpose x: fp32 NCHW -> bf16 NHWC (width-256 rows). Block = (b,h).
// ---------------------------------------------------------------------------
__global__ __launch_bounds__(256) void k_tr(const float* __restrict__ x,
                                            ushort_t* __restrict__ xbf) {
    int bid = blockIdx.x;
    int h = bid & 255, b = bid >> 8;
    int t = threadIdx.x;
    for (int it = 0; it < 8; ++it) {
        int idx = t + it * 256;  // (w, g)
        int g = idx & 7, w = idx >> 3;
        const float* src = x + (((size_t)(b * 64 + g * 8) * 256 + h) * 256 + w);
        short8 v;
#pragma unroll
        for (int j = 0; j < 8; ++j) v[j] = (short)f2bf(src[(size_t)j * 65536]);
        *(short8*)(xbf + (((size_t)(b * 256 + h) * 256 + w) * 64 + g * 8)) = v;
    }
}

// ---------------------------------------------------------------------------
// Stage one 16-ci pixel chunk (6 rows x 258 pix): 4 x gload_lds16 per wave,
// stripes of 196 slots (overlaps write identical data; pad never read).
// Inverse swizzle baked into per-lane source address.
// ---------------------------------------------------------------------------
#define STAGE_X(chunk, xbase)                                                    \
    {                                                                            \
        _Pragma("unroll")                                                        \
        for (int i_ = 0; i_ < 4; ++i_) {                                         \
            int base_ = wv * 196 + i_ * 64;                                      \
            int S_ = base_ + lane;                                               \
            S_ = S_ < XCH ? S_ : XCH - 1;                                        \
            int r_ = (S_ >= 2600) ? 5                                            \
                     : (S_ >= 2080) ? 4                                          \
                     : (S_ >= 1560) ? 3                                          \
                     : (S_ >= 1040) ? 2 : (S_ >= 520 ? 1 : 0);                   \
            int rem_ = S_ - r_ * 520;                                            \
            int mg_ = rem_ >> 3, sl_ = rem_ & 7;                                 \
            int sp_ = sl_ ^ (mg_ & 7);                                           \
            int p_ = mg_ * 4 + (sp_ >> 1), g_ = sp_ & 1;                         \
            int wsx_ = p_ - 1;                                                   \
            bool edge_ = (unsigned)wsx_ >= 256u;                                 \
            const ushort_t* rp_ = rbp[r_];                                       \
            const ushort_t* src_ =                                               \
                edge_ ? zv : (rp_ + wsx_ * 64 + (chunk)*16 + g_ * 8);            \
            gload_lds16(src_, xs + (xbase) + (size_t)base_ * 8);                 \
        }                                                                        \
    }

// Stage one 18-row weight slice (chunk): 2 x gload_lds16 per wave.
// Row r of slice = packed row (( (r>>1)*4 + chunk)*2 + (r&1)).
#define WOFF(row, chunk) ((size_t)((((row) >> 1) * 4 + (chunk)) * 2 + ((row)&1)) * 512)
#define STAGE_W(chunk, wbase)                                                    \
    {                                                                            \
        gload_lds16(wp + WOFF(wv, chunk) + lane * 8,                             \
                    xs + (wbase) + (size_t)wv * 512);                            \
        int rb_ = (wv < 2) ? 16 + wv : 18 + (wv & 1);                            \
        int rs_ = (wv < 2) ? 16 + wv : 17;                                       \
        gload_lds16(wp + WOFF(rs_, chunk) + lane * 8,                            \
                    xs + (wbase) + (size_t)rb_ * 512);                           \
    }

// Compute one chunk: A and B both via ds_read (pure lgkmcnt domain).
#define COMPUTE(wbase, xbase)                                                    \
    {                                                                            \
        __builtin_amdgcn_s_setprio(1);                                           \
        _Pragma("unroll")                                                        \
        for (int t_ = 0; t_ < 9; ++t_) {                                         \
            short8 a0 = *(const short8*)(xs + (wbase) + (size_t)(t_ * 2) * 512 + lane * 8); \
            short8 a1 = *(const short8*)(xs + (wbase) + (size_t)(t_ * 2 + 1) * 512 + lane * 8); \
            const int dwx_ = t_ % 3, rr_ = t_ / 3;                               \
            const int rowIdx_ = rbase + rr_;                                     \
            _Pragma("unroll")                                                    \
            for (int pt_ = 0; pt_ < 2; ++pt_) {                                  \
                int p_ = pw0 + pt_ * 32 + l31 + dwx_;                            \
                int mg_ = p_ >> 2;                                               \
                int sl_ = ((p_ & 3) * 2 + lhi) ^ (mg_ & 7);                      \
                short8 bf = *(const short8*)(                                    \
                    xs + (xbase) + (size_t)(rowIdx_ * 520 + mg_ * 8 + sl_) * 8); \
                acc[0][pt_] = __builtin_amdgcn_mfma_f32_32x32x16_bf16(           \
                    a0, bf, acc[0][pt_], 0, 0, 0);                               \
                acc[1][pt_] = __builtin_amdgcn_mfma_f32_32x32x16_bf16(           \
                    a1, bf, acc[1][pt_], 0, 0, 0);                               \
            }                                                                    \
        }                                                                        \
        __builtin_amdgcn_s_setprio(0);                                           \
    }

// ---------------------------------------------------------------------------
// 3x3 conv 64->64. Block = (b, 4-row band) XCD-swizzled; 16 waves =
// 4 rows x 4 pixel-quarters; each wave 64co x 64pix.
// OMODE: 0 = bf16 NHWC + leaky; 1 = bf16 NCHW + leaky; 2 = fp32 NCHW + bias.
// ---------------------------------------------------------------------------
template <int OMODE>
__global__ __launch_bounds__(1024, 4) void k_conv(
    const ushort_t* __restrict__ in, const ushort_t* __restrict__ zv,
    const ushort_t* __restrict__ wp, const float* __restrict__ bias,
    void* __restrict__ outp) {
    extern __shared__ __align__(16) ushort_t xs[];  // [wb0][wb1][xb0][xb1]
    const int tid = threadIdx.x;
    const int lane = tid & 63;
    const int wv = tid >> 6;                        // 0..15
    const unsigned bid = blockIdx.x;
    const unsigned L = (bid & 7u) * 128u + (bid >> 3);  // 1024 = 8*128 bijective
    const int h0 = (L & 63) * 4, b = L >> 6;
    const int l31 = lane & 31, lhi = lane >> 5;
    const int pw0 = (wv & 3) * 64;                  // pixel quarter
    const int rbase = wv >> 2;                      // output row 0..3
    const int ro = h0 + rbase;

    const ushort_t* rbp[6];
    rbp[0] = (h0 > 0) ? in + ((size_t)(b * 256 + h0 - 1)) * 16384 : zv;
#pragma unroll
    for (int r = 1; r < 5; ++r)
        rbp[r] = in + ((size_t)(b * 256 + h0 + r - 1)) * 16384;
    rbp[5] = (h0 < 252) ? in + ((size_t)(b * 256 + h0 + 4)) * 16384 : zv;

    f32x16 acc[2][2];
#pragma unroll
    for (int a = 0; a < 2; ++a)
#pragma unroll
        for (int c = 0; c < 2; ++c) acc[a][c] = (f32x16)0.0f;

    STAGE_W(0, WB0); STAGE_X(0, XB0);   // 6 per wave
    STAGE_W(1, WB1); STAGE_X(1, XB1);   // 12 outstanding
    VMCNT(6);   // chunk0 resident; chunk1 in flight
    RBAR(); SCHED0();
    COMPUTE(WB0, XB0);
    RBAR();
    STAGE_W(2, WB0); STAGE_X(2, XB0);
    VMCNT(6);   // chunk1 resident; chunk2 in flight
    RBAR(); SCHED0();
    COMPUTE(WB1, XB1);
    RBAR();
    STAGE_W(3, WB1); STAGE_X(3, XB1);
    VMCNT(6);   // chunk2 resident; chunk3 in flight
    RBAR(); SCHED0();
    COMPUTE(WB0, XB0);
    VMCNT(0);   // chunk3 resident
    RBAR(); SCHED0();
    COMPUTE(WB1, XB1);

    // Epilogue. D layout: col(pix)=lane&31, row(co)=(reg&3)+8*(reg>>2)+4*(lane>>5)
    const int co_b = 4 * lhi;
    if (OMODE == 0) {
        ushort_t* outb = (ushort_t*)outp + ((size_t)(b * 256 + ro)) * 16384;
#pragma unroll
        for (int ct = 0; ct < 2; ++ct)
#pragma unroll
            for (int pt = 0; pt < 2; ++pt) {
                int pix = pw0 + pt * 32 + l31;
                ushort_t* po = outb + (size_t)pix * 64 + ct * 32 + co_b;
#pragma unroll
                for (int q = 0; q < 4; ++q) {
                    float4v bv = *(const float4v*)(bias + ct * 32 + co_b + 8 * q);
                    short4v sv;
#pragma unroll
                    for (int m = 0; m < 4; ++m) {
                        float v = lrelu(acc[ct][pt][q * 4 + m] + bv[m]);
                        sv[m] = (short)f2bf(v);
                    }
                    *(short4v*)(po + 8 * q) = sv;
                }
            }
    } else if (OMODE == 1) {
        ushort_t* pb = (ushort_t*)outp + (((size_t)b * 64) << 16) + ro * 256;
#pragma unroll
        for (int ct = 0; ct < 2; ++ct)
#pragma unroll
            for (int pt = 0; pt < 2; ++pt) {
                int pix = pw0 + pt * 32 + l31;
#pragma unroll
                for (int q = 0; q < 4; ++q) {
                    float4v bv = *(const float4v*)(bias + ct * 32 + co_b + 8 * q);
#pragma unroll
                    for (int m = 0; m < 4; ++m) {
                        int c = ct * 32 + co_b + 8 * q + m;
                        float v = lrelu(acc[ct][pt][q * 4 + m] + bv[m]);
                        pb[((size_t)c << 16) + pix] = f2bf(v);
                    }
                }
            }
    } else {
        float* pb = (float*)outp + (((size_t)b * 64) << 16) + ro * 256;
#pragma unroll
        for (int ct = 0; ct < 2; ++ct)
#pragma unroll
            for (int pt = 0; pt < 2; ++pt) {
                int pix = pw0 + pt * 32 + l31;
#pragma unroll
                for (int q = 0; q < 4; ++q) {
                    float4v bv = *(const float4v*)(bias + ct * 32 + co_b + 8 * q);
#pragma unroll
                    for (int m = 0; m < 4; ++m) {
                        int c = ct * 32 + co_b + 8 * q + m;
                        pb[((size_t)c << 16) + pix] = acc[ct][pt][q * 4 + m] + bv[m];
                    }
                }
            }
    }
}

// ---------------------------------------------------------------------------
// Final depthwise: out[b][c][h][w] += sum_tap ktr[b][tap][c] * f2[b][c][h'][w']
// Block = (b, c, 8-row band); f2 is bf16 NCHW. High occupancy, ~roofline.
// ---------------------------------------------------------------------------
__global__ __launch_bounds__(256) void k_fin(const ushort_t* __restrict__ f2,
                                             const float* __restrict__ ktr,
                                             float* __restrict__ out) {
    __shared__ __align__(16) ushort_t s[10 * 272];
    const unsigned bid = blockIdx.x;
    const unsigned L = (bid & 7u) * 4096u + (bid >> 3);  // bijective, 32768=8*4096
    const int hb = L & 31, c = (L >> 5) & 63, b = L >> 11;
    const int h0 = hb * 8;
    const int w = threadIdx.x;

    const ushort_t* f2c = f2 + (((size_t)(b * 64 + c)) << 16);
    for (int i = w; i < 320; i += 256) {
        int r = i >> 5, seg = i & 31;
        int hs = h0 - 1 + r;
        short8 v = (short8)0;
        if ((unsigned)hs < 256u) v = *(const short8*)(f2c + hs * 256 + seg * 8);
        *(short8*)(&s[r * 272 + 8 + seg * 8]) = v;
        if (seg == 0) s[r * 272 + 7] = 0;
        if (seg == 31) s[r * 272 + 264] = 0;
    }
    __syncthreads();

    float kv[9];
#pragma unroll
    for (int t9 = 0; t9 < 9; ++t9) kv[t9] = ktr[b * 576 + t9 * 64 + c];

    float lv[10], cv[10], rv[10];
#pragma unroll
    for (int r = 0; r < 10; ++r) {
        lv[r] = bf2f(s[r * 272 + 7 + w]);
        cv[r] = bf2f(s[r * 272 + 8 + w]);
        rv[r] = bf2f(s[r * 272 + 9 + w]);
    }

    float* ob = out + (((size_t)(b * 64 + c)) << 16) + h0 * 256 + w;
#pragma unroll
    for (int rr = 0; rr < 8; ++rr) {
        float dwv = 0.f;
#pragma unroll
        for (int r3 = 0; r3 < 3; ++r3) {
            dwv = fmaf(kv[r3 * 3 + 0], lv[rr + r3], dwv);
            dwv = fmaf(kv[r3 * 3 + 1], cv[rr + r3], dwv);
            dwv = fmaf(kv[r3 * 3 + 2], rv[rr + r3], dwv);
        }
        float* po = ob + rr * 256;
        *po = *po + dwv;
    }
}

// ---------------------------------------------------------------------------
extern "C" void kernel_launch(void* const* d_in, const int* in_sizes, int n_in,
                              void* d_out, int out_size, void* d_ws, size_t ws_size,
                              hipStream_t stream) {
    const float* x   = (const float*)d_in[0];
    const float* t   = (const float*)d_in[1];
    const float* tW1 = (const float*)d_in[2];
    const float* tW2 = (const float*)d_in[3];
    const float* fW1 = (const float*)d_in[4];
    const float* fb1 = (const float*)d_in[5];
    const float* fW2 = (const float*)d_in[6];
    const float* fb2 = (const float*)d_in[7];
    const float* kW1 = (const float*)d_in[8];
    const float* kW2 = (const float*)d_in[9];
    const float* cW  = (const float*)d_in[10];
    const float* cb  = (const float*)d_in[11];

    // ws: [ktr 36K @0][wp 216K @65536][zv 32K @294912]
    //     [R1 128MB @512K]: xbf (until conv<2> done), then f2
    //     [R2 128MB @512K+128MB]: f1
    char* ws = (char*)d_ws;
    float*    ktr  = (float*)ws;
    ushort_t* wp   = (ushort_t*)(ws + 65536);
    ushort_t* zv   = (ushort_t*)(ws + 294912);
    ushort_t* xbf  = (ushort_t*)(ws + (512u << 10));                       // R1
    ushort_t* f1bf = (ushort_t*)(ws + (512u << 10) + ((size_t)128 << 20)); // R2
    ushort_t* f2n  = xbf;  // R1 reused after conv<2> (last xbf reader)
    float*    out  = (float*)d_out;

    hipFuncSetAttribute(reinterpret_cast<const void*>(&k_conv<0>),
                        hipFuncAttributeMaxDynamicSharedMemorySize, DYN_LDS);
    hipFuncSetAttribute(reinterpret_cast<const void*>(&k_conv<1>),
                        hipFuncAttributeMaxDynamicSharedMemorySize, DYN_LDS);
    hipFuncSetAttribute(reinterpret_cast<const void*>(&k_conv<2>),
                        hipFuncAttributeMaxDynamicSharedMemorySize, DYN_LDS);

    k_tiny<<<dim3(16), dim3(64), 0, stream>>>(t, tW1, tW2, kW1, kW2, ktr);
    k_zrow<<<dim3(8), dim3(256), 0, stream>>>(zv);
    k_pack<<<dim3((3 * 36864 + 255) / 256), dim3(256), 0, stream>>>(fW1, fW2, cW, wp);
    k_tr<<<dim3(4096), dim3(256), 0, stream>>>(x, xbf);

    // conv1: x -> f1 (bf16 NHWC); conv3: x -> d_out (fp32 NCHW, +cb);
    // conv2: f1 -> f2 (bf16 NCHW); k_fin: out += dw(f2)*gate.
    k_conv<0><<<dim3(1024), dim3(1024), DYN_LDS, stream>>>(xbf, zv, wp, fb1, (void*)f1bf);
    k_conv<2><<<dim3(1024), dim3(1024), DYN_LDS, stream>>>(xbf, zv, wp + 2 * 36864, cb, (void*)out);
    k_conv<1><<<dim3(1024), dim3(1024), DYN_LDS, stream>>>(f1bf, zv, wp + 36864, fb2, (void*)f2n);
    k_fin<<<dim3(32768), dim3(256), 0, stream>>>(f2n, ktr, out);
}

// Round 14
// 640.015 us; speedup vs baseline: 1.5049x; 1.5049x over previous
//
#include <hip/hip_runtime.h>
#include <cstdint>

// B=16, C=64, H=W=256. 3x3 convs via bf16 MFMA implicit GEMM.
// Round 14: composition of best measured pieces. Conv core = round 10's
// 512-thread weights-in-LDS pure-LDS-compute kernel (measured ~119us/conv)
// for ALL THREE convs (conv<2> is a plain conv now); dynamic depthwise =
// round 6-9's high-occupancy k_fin (~100us, near roofline). No new
// structural experiments this round.
using short8  = __attribute__((ext_vector_type(8))) short;
using short4v = __attribute__((ext_vector_type(4))) short;
using f32x16  = __attribute__((ext_vector_type(16))) float;
using float4v = __attribute__((ext_vector_type(4))) float;
typedef unsigned short ushort_t;

#define CSLOTS 2080       // 4 rows x 520 slots per pixel chunk
#define BSLOTS 2144       // padded (stage stripes overrun to 2139)
#define XSH (BSLOTS * 8)  // shorts per pixel buffer = 17152
#define WSH 36864         // weight shorts (72 frag-rows x 512)
#define DYN_LDS ((WSH + 2 * XSH) * 2)  // 142336 bytes

__device__ __forceinline__ float lrelu(float x) { return x > 0.f ? x : 0.1f * x; }

__device__ __forceinline__ ushort_t f2bf(float f) {
    union { float f; unsigned u; } v; v.f = f;
    unsigned r = (v.u + 0x7FFFu + ((v.u >> 16) & 1u)) >> 16;
    return (ushort_t)r;
}
__device__ __forceinline__ float bf2f(ushort_t b) {
    union { unsigned u; float f; } v; v.u = ((unsigned)b) << 16; return v.f;
}

// async 16B global -> LDS (dest = wave-uniform base; HW adds lane*16)
__device__ __forceinline__ void gload_lds16(const ushort_t* g, ushort_t* l) {
    __builtin_amdgcn_global_load_lds(
        (const __attribute__((address_space(1))) void*)g,
        (__attribute__((address_space(3))) void*)l, 16, 0, 0);
}

#define VMCNT(n) asm volatile("s_waitcnt vmcnt(" #n ")" ::: "memory")
#define RBAR() __builtin_amdgcn_s_barrier()
#define SCHED0() __builtin_amdgcn_sched_barrier(0)

// ---------------------------------------------------------------------------
// Tiny branch: ktr[b][tap][c] = leaky(kern) * sigmoid-gate (mv folded in).
// ---------------------------------------------------------------------------
__global__ void k_tiny(const float* __restrict__ t, const float* __restrict__ tW1,
                       const float* __restrict__ tW2, const float* __restrict__ kW1,
                       const float* __restrict__ kW2, float* __restrict__ ktr) {
    int b = blockIdx.x;
    int c = threadIdx.x;  // 64
    __shared__ float h1[64], g1[64];
    float ts = t[b];
    h1[c] = lrelu(ts * tW1[c]);
    g1[c] = lrelu(ts * kW1[c]);
    __syncthreads();
    float s = 0.f;
    for (int j = 0; j < 64; ++j) s = fmaf(tW2[c * 64 + j], h1[j], s);
    float mvv = 1.f / (1.f + expf(-s));
    for (int q = 0; q < 9; ++q) {
        float s2 = 0.f;
        for (int j = 0; j < 64; ++j) s2 = fmaf(kW2[(c * 9 + q) * 64 + j], g1[j], s2);
        ktr[b * 576 + q * 64 + c] = lrelu(s2) * mvv;
    }
}

// ---------------------------------------------------------------------------
// Zero row buffer (edge-redirect source for staging).
// ---------------------------------------------------------------------------
__global__ void k_zrow(ushort_t* __restrict__ z) {
    int i = blockIdx.x * 256 + threadIdx.x;  // 2048 threads, 16384 shorts
    *(short8*)(z + (size_t)i * 8) = (short8)0;
}

// ---------------------------------------------------------------------------
// Pack three 64x64x3x3 weight tensors into MFMA A-fragment order (bf16).
// flat = ((t*4 + chunk)*2 + ct)*512 + lane*8 + j
//   = W[co = ct*32 + (lane&31)][ci = chunk*16 + (lane>>5)*8 + j], tap t
// ---------------------------------------------------------------------------
__global__ void k_pack(const float* __restrict__ w1, const float* __restrict__ w2,
                       const float* __restrict__ w3, ushort_t* __restrict__ wp) {
    int idx = blockIdx.x * 256 + threadIdx.x;
    if (idx >= 3 * 36864) return;
    int conv = idx / 36864, r = idx % 36864;
    const float* W = conv == 0 ? w1 : (conv == 1 ? w2 : w3);
    int j = r & 7, lane = (r >> 3) & 63, ct = (r >> 9) & 1, chunk = (r >> 10) & 3,
        t = r >> 12;
    int co = ct * 32 + (lane & 31);
    int ci = chunk * 16 + (lane >> 5) * 8 + j;
    wp[idx] = f2bf(W[(co * 64 + ci) * 9 + t]);
}

// ---------------------------------------------------------------------------
// Transpose x: fp32 NCHW -> bf16 NHWC (width-256 rows). Block = (b,h).
// ---------------------------------------------------------------------------
__global__ __launch_bounds__(256) void k_tr(const float* __restrict__ x,
                                            ushort_t* __restrict__ xbf) {
    int bid = blockIdx.x;
    int h = bid & 255, b = bid >> 8;
    int t = threadIdx.x;
    for (int it = 0; it < 8; ++it) {
        int idx = t + it * 256;  // (w, g)
        int g = idx & 7, w = idx >> 3;
        const float* src = x + (((size_t)(b * 64 + g * 8) * 256 + h) * 256 + w);
        short8 v;
#pragma unroll
        for (int j = 0; j < 8; ++j) v[j] = (short)f2bf(src[(size_t)j * 65536]);
        *(short8*)(xbf + (((size_t)(b * 256 + h) * 256 + w) * 64 + g * 8)) = v;
    }
}

// ---------------------------------------------------------------------------
// Stage one 16-ci chunk: 4 rows x 258 pix, 5 x gload_lds16 per wave (8 waves,
// stripes of 260 slots). Inverse swizzle baked into per-lane source address.
// ---------------------------------------------------------------------------
#define STAGE4(chunk, bufbase)                                                   \
    {                                                                            \
        _Pragma("unroll")                                                        \
        for (int i_ = 0; i_ < 5; ++i_) {                                         \
            int base_ = wv * 260 + i_ * 64;                                      \
            int S_ = base_ + lane;                                               \
            S_ = S_ < CSLOTS ? S_ : CSLOTS - 1;                                  \
            int r_ = (S_ >= 1560) ? 3 : ((S_ >= 1040) ? 2 : ((S_ >= 520) ? 1 : 0)); \
            int rem_ = S_ - r_ * 520;                                            \
            int mg_ = rem_ >> 3, sl_ = rem_ & 7;                                 \
            int sp_ = sl_ ^ (mg_ & 7);                                           \
            int p_ = mg_ * 4 + (sp_ >> 1), g_ = sp_ & 1;                         \
            int wsx_ = p_ - 1;                                                   \
            bool edge_ = (unsigned)wsx_ >= 256u;                                 \
            const ushort_t* rp_ =                                                \
                (r_ == 0) ? rb0 : ((r_ == 1) ? rb1 : ((r_ == 2) ? rb2 : rb3));   \
            const ushort_t* src_ =                                               \
                edge_ ? zv : (rp_ + wsx_ * 64 + (chunk)*16 + g_ * 8);            \
            gload_lds16(src_, xs + (bufbase) + (size_t)base_ * 8);               \
        }                                                                        \
    }

// ---------------------------------------------------------------------------
// Compute one 16-ci chunk: A (weights) and B (pixels) both from LDS.
// Pure lgkmcnt domain -> staging vmcnt ops float across this freely.
// ---------------------------------------------------------------------------
__device__ __forceinline__ void computeG(const ushort_t* __restrict__ wlds,
                                         const ushort_t* __restrict__ xs,
                                         int bufbase, int chunk, int lane, int pw0,
                                         int l31, int lhi, int rbase,
                                         f32x16 (&acc)[2][2]) {
    __builtin_amdgcn_s_setprio(1);
#pragma unroll
    for (int t = 0; t < 9; ++t) {
        const int off = ((t * 4 + chunk) * 2) * 512 + lane * 8;
        short8 a0 = *(const short8*)(wlds + off);
        short8 a1 = *(const short8*)(wlds + off + 512);
        const int dwx = t % 3, rr = t / 3;
        const int rowIdx = rbase + rr;
#pragma unroll
        for (int pt = 0; pt < 2; ++pt) {
            int p = pw0 + pt * 32 + l31 + dwx;
            int mg = p >> 2;
            int sl = ((p & 3) * 2 + lhi) ^ (mg & 7);
            short8 bf = *(const short8*)(
                xs + bufbase + (size_t)(rowIdx * 520 + mg * 8 + sl) * 8);
            acc[0][pt] = __builtin_amdgcn_mfma_f32_32x32x16_bf16(a0, bf, acc[0][pt], 0, 0, 0);
            acc[1][pt] = __builtin_amdgcn_mfma_f32_32x32x16_bf16(a1, bf, acc[1][pt], 0, 0, 0);
        }
    }
    __builtin_amdgcn_s_setprio(0);
}

// ---------------------------------------------------------------------------
// Generic 3x3 conv 64->64. Block = (b, h-pair) XCD-swizzled; 8 waves, each
// 64 c_out x 64 pixels; weights preloaded to LDS once. OMODE:
// 0 = bf16 NHWC + leaky; 1 = bf16 NCHW + leaky; 2 = fp32 NCHW + bias.
// ---------------------------------------------------------------------------
template <int OMODE>
__global__ __launch_bounds__(512, 2) void k_conv(
    const ushort_t* __restrict__ in, const ushort_t* __restrict__ zv,
    const ushort_t* __restrict__ wp, const float* __restrict__ bias,
    void* __restrict__ outp) {
    extern __shared__ char smem_raw[];
    ushort_t* wlds = (ushort_t*)smem_raw;        // 36864 shorts (72 KB)
    ushort_t* xs = wlds + WSH;                   // 2 x 17152 shorts (68.6 KB)

    const int tid = threadIdx.x;
    const int lane = tid & 63;
    const int wv = tid >> 6;                     // 0..7
    const unsigned bid = blockIdx.x;
    const unsigned L = (bid & 7u) * 256u + (bid >> 3);  // 2048 = 8*256 bijective
    const int h0 = (L & 127) * 2, b = L >> 7;
    const int l31 = lane & 31, lhi = lane >> 5;
    const int pw0 = (wv & 3) * 64;               // pixel quarter
    const int rbase = wv >> 2;                   // 0 or 1
    const int ro = h0 + rbase;                   // this wave's output row

    const ushort_t* rb0 = (h0 > 0)    ? in + ((size_t)(b * 256 + h0 - 1)) * 16384 : zv;
    const ushort_t* rb1 =               in + ((size_t)(b * 256 + h0)) * 16384;
    const ushort_t* rb2 =               in + ((size_t)(b * 256 + h0 + 1)) * 16384;
    const ushort_t* rb3 = (h0 < 254)  ? in + ((size_t)(b * 256 + h0 + 2)) * 16384 : zv;

    f32x16 acc[2][2];
#pragma unroll
    for (int a = 0; a < 2; ++a)
#pragma unroll
        for (int c = 0; c < 2; ++c) acc[a][c] = (f32x16)0.0f;

    // Prologue: weights (9 loads/wave, linear) + stage chunk0/chunk1.
#pragma unroll
    for (int i = 0; i < 9; ++i) {
        int idx = wv * 9 + i;  // 0..71, exact
        gload_lds16(wp + (size_t)idx * 512 + lane * 8, wlds + (size_t)idx * 512);
    }
    STAGE4(0, 0);
    STAGE4(1, XSH);
    VMCNT(5);  // retire weights + S0; keep S1 in flight
    RBAR(); SCHED0();
    computeG(wlds, xs, 0, 0, lane, pw0, l31, lhi, rbase, acc);
    RBAR();                       // all waves done reading buf0
    STAGE4(2, 0);
    VMCNT(5);                     // retire S1; keep S2
    RBAR(); SCHED0();
    computeG(wlds, xs, XSH, 1, lane, pw0, l31, lhi, rbase, acc);
    RBAR();
    STAGE4(3, XSH);
    VMCNT(5);                     // retire S2; keep S3
    RBAR(); SCHED0();
    computeG(wlds, xs, 0, 2, lane, pw0, l31, lhi, rbase, acc);
    VMCNT(0);                     // S3 resident (pipeline epilogue)
    RBAR(); SCHED0();
    computeG(wlds, xs, XSH, 3, lane, pw0, l31, lhi, rbase, acc);

    // Epilogue. D layout: col(pix)=lane&31, row(co)=(reg&3)+8*(reg>>2)+4*(lane>>5)
    const int co_b = 4 * lhi;
    if (OMODE == 0) {
        // bf16 NHWC + leaky
        ushort_t* outb = (ushort_t*)outp + ((size_t)(b * 256 + ro)) * 16384;
#pragma unroll
        for (int ct = 0; ct < 2; ++ct)
#pragma unroll
            for (int pt = 0; pt < 2; ++pt) {
                int pix = pw0 + pt * 32 + l31;
                ushort_t* po = outb + (size_t)pix * 64 + ct * 32 + co_b;
#pragma unroll
                for (int q = 0; q < 4; ++q) {
                    float4v bv = *(const float4v*)(bias + ct * 32 + co_b + 8 * q);
                    short4v sv;
#pragma unroll
                    for (int m = 0; m < 4; ++m) {
                        float v = lrelu(acc[ct][pt][q * 4 + m] + bv[m]);
                        sv[m] = (short)f2bf(v);
                    }
                    *(short4v*)(po + 8 * q) = sv;
                }
            }
    } else if (OMODE == 1) {
        // bf16 NCHW + leaky
        ushort_t* pb = (ushort_t*)outp + (((size_t)b * 64) << 16) + ro * 256;
#pragma unroll
        for (int ct = 0; ct < 2; ++ct)
#pragma unroll
            for (int pt = 0; pt < 2; ++pt) {
                int pix = pw0 + pt * 32 + l31;
#pragma unroll
                for (int q = 0; q < 4; ++q) {
                    float4v bv = *(const float4v*)(bias + ct * 32 + co_b + 8 * q);
#pragma unroll
                    for (int m = 0; m < 4; ++m) {
                        int c = ct * 32 + co_b + 8 * q + m;
                        float v = lrelu(acc[ct][pt][q * 4 + m] + bv[m]);
                        pb[((size_t)c << 16) + pix] = f2bf(v);
                    }
                }
            }
    } else {
        // fp32 NCHW + bias (no activation)
        float* pb = (float*)outp + (((size_t)b * 64) << 16) + ro * 256;
#pragma unroll
        for (int ct = 0; ct < 2; ++ct)
#pragma unroll
            for (int pt = 0; pt < 2; ++pt) {
                int pix = pw0 + pt * 32 + l31;
#pragma unroll
                for (int q = 0; q < 4; ++q) {
                    float4v bv = *(const float4v*)(bias + ct * 32 + co_b + 8 * q);
#pragma unroll
                    for (int m = 0; m < 4; ++m) {
                        int c = ct * 32 + co_b + 8 * q + m;
                        pb[((size_t)c << 16) + pix] = acc[ct][pt][q * 4 + m] + bv[m];
                    }
                }
            }
    }
}

// ---------------------------------------------------------------------------
// Final depthwise: out[b][c][h][w] += sum_tap ktr[b][tap][c] * f2[b][c][h'][w']
// Block = (b, c, 8-row band); f2 is bf16 NCHW. High occupancy, ~roofline.
// ---------------------------------------------------------------------------
__global__ __launch_bounds__(256) void k_fin(const ushort_t* __restrict__ f2,
                                             const float* __restrict__ ktr,
                                             float* __restrict__ out) {
    __shared__ __align__(16) ushort_t s[10 * 272];
    const unsigned bid = blockIdx.x;
    const unsigned L = (bid & 7u) * 4096u + (bid >> 3);  // bijective, 32768=8*4096
    const int hb = L & 31, c = (L >> 5) & 63, b = L >> 11;
    const int h0 = hb * 8;
    const int w = threadIdx.x;

    const ushort_t* f2c = f2 + (((size_t)(b * 64 + c)) << 16);
    for (int i = w; i < 320; i += 256) {
        int r = i >> 5, seg = i & 31;
        int hs = h0 - 1 + r;
        short8 v = (short8)0;
        if ((unsigned)hs < 256u) v = *(const short8*)(f2c + hs * 256 + seg * 8);
        *(short8*)(&s[r * 272 + 8 + seg * 8]) = v;
        if (seg == 0) s[r * 272 + 7] = 0;
        if (seg == 31) s[r * 272 + 264] = 0;
    }
    __syncthreads();

    float kv[9];
#pragma unroll
    for (int t9 = 0; t9 < 9; ++t9) kv[t9] = ktr[b * 576 + t9 * 64 + c];

    float lv[10], cv[10], rv[10];
#pragma unroll
    for (int r = 0; r < 10; ++r) {
        lv[r] = bf2f(s[r * 272 + 7 + w]);
        cv[r] = bf2f(s[r * 272 + 8 + w]);
        rv[r] = bf2f(s[r * 272 + 9 + w]);
    }

    float* ob = out + (((size_t)(b * 64 + c)) << 16) + h0 * 256 + w;
#pragma unroll
    for (int rr = 0; rr < 8; ++rr) {
        float dwv = 0.f;
#pragma unroll
        for (int r3 = 0; r3 < 3; ++r3) {
            dwv = fmaf(kv[r3 * 3 + 0], lv[rr + r3], dwv);
            dwv = fmaf(kv[r3 * 3 + 1], cv[rr + r3], dwv);
            dwv = fmaf(kv[r3 * 3 + 2], rv[rr + r3], dwv);
        }
        float* po = ob + rr * 256;
        *po = *po + dwv;
    }
}

// ---------------------------------------------------------------------------
extern "C" void kernel_launch(void* const* d_in, const int* in_sizes, int n_in,
                              void* d_out, int out_size, void* d_ws, size_t ws_size,
                              hipStream_t stream) {
    const float* x   = (const float*)d_in[0];
    const float* t   = (const float*)d_in[1];
    const float* tW1 = (const float*)d_in[2];
    const float* tW2 = (const float*)d_in[3];
    const float* fW1 = (const float*)d_in[4];
    const float* fb1 = (const float*)d_in[5];
    const float* fW2 = (const float*)d_in[6];
    const float* fb2 = (const float*)d_in[7];
    const float* kW1 = (const float*)d_in[8];
    const float* kW2 = (const float*)d_in[9];
    const float* cW  = (const float*)d_in[10];
    const float* cb  = (const float*)d_in[11];

    // ws: [ktr 36K @0][wp 216K @65536][zv 32K @294912]
    //     [R1 128MB @512K]: xbf (until conv<2> done), then f2
    //     [R2 128MB @512K+128MB]: f1
    char* ws = (char*)d_ws;
    float*    ktr  = (float*)ws;
    ushort_t* wp   = (ushort_t*)(ws + 65536);
    ushort_t* zv   = (ushort_t*)(ws + 294912);
    ushort_t* xbf  = (ushort_t*)(ws + (512u << 10));                       // R1
    ushort_t* f1bf = (ushort_t*)(ws + (512u << 10) + ((size_t)128 << 20)); // R2
    ushort_t* f2n  = xbf;  // R1 reused after conv<2> (last xbf reader)
    float*    out  = (float*)d_out;

    hipFuncSetAttribute(reinterpret_cast<const void*>(&k_conv<0>),
                        hipFuncAttributeMaxDynamicSharedMemorySize, DYN_LDS);
    hipFuncSetAttribute(reinterpret_cast<const void*>(&k_conv<1>),
                        hipFuncAttributeMaxDynamicSharedMemorySize, DYN_LDS);
    hipFuncSetAttribute(reinterpret_cast<const void*>(&k_conv<2>),
                        hipFuncAttributeMaxDynamicSharedMemorySize, DYN_LDS);

    k_tiny<<<dim3(16), dim3(64), 0, stream>>>(t, tW1, tW2, kW1, kW2, ktr);
    k_zrow<<<dim3(8), dim3(256), 0, stream>>>(zv);
    k_pack<<<dim3((3 * 36864 + 255) / 256), dim3(256), 0, stream>>>(fW1, fW2, cW, wp);
    k_tr<<<dim3(4096), dim3(256), 0, stream>>>(x, xbf);

    // conv1: x -> f1 (bf16 NHWC); conv3: x -> d_out (fp32 NCHW, +cb);
    // conv2: f1 -> f2 (bf16 NCHW); k_fin: out += dw(f2)*gate.
    k_conv<0><<<dim3(2048), dim3(512), DYN_LDS, stream>>>(xbf, zv, wp, fb1, (void*)f1bf);
    k_conv<2><<<dim3(2048), dim3(512), DYN_LDS, stream>>>(xbf, zv, wp + 2 * 36864, cb, (void*)out);
    k_conv<1><<<dim3(2048), dim3(512), DYN_LDS, stream>>>(f1bf, zv, wp + 36864, fb2, (void*)f2n);
    k_fin<<<dim3(32768), dim3(256), 0, stream>>>(f2n, ktr, out);
}

// Round 15
// 609.809 us; speedup vs baseline: 1.5795x; 1.0495x over previous
//
#include <hip/hip_runtime.h>
#include <cstdint>

// B=16, C=64, H=W=256. 3x3 convs via bf16 MFMA implicit GEMM.
// Round 15: 2 independent blocks per CU (barrier decoupling). 256-thr /
// 4-wave / 1-row blocks; weights single-buffered in LDS (re-staged per chunk,
// part of the same vmcnt FIFO: uniform VMCNT(7)); pixels double-buffered
// (3-row 16-ci chunks). LDS 72704B -> 2 blocks/CU. Pure-LDS compute cluster.
using short8  = __attribute__((ext_vector_type(8))) short;
using short4v = __attribute__((ext_vector_type(4))) short;
using f32x16  = __attribute__((ext_vector_type(16))) float;
using float4v = __attribute__((ext_vector_type(4))) float;
typedef unsigned short ushort_t;

#define CHUNK_ROW 520       // 65 macro-groups x 8 slots (16 ci)
#define CHUNK_SLOTS 1560    // 3 rows
#define BUF_SLOTS 1632      // padded (stage stripes overrun to 1617)
#define XSHW (BUF_SLOTS * 8)  // shorts per pixel buffer = 13056
#define WSHW (20 * 512)       // shorts in weight buffer (18 rows + 2 pad)
#define XB0 WSHW
#define XB1 (WSHW + XSHW)
#define DYN_LDS ((WSHW + 2 * XSHW) * 2)  // 72704 bytes -> 2 blocks/CU

__device__ __forceinline__ float lrelu(float x) { return x > 0.f ? x : 0.1f * x; }

__device__ __forceinline__ ushort_t f2bf(float f) {
    union { float f; unsigned u; } v; v.f = f;
    unsigned r = (v.u + 0x7FFFu + ((v.u >> 16) & 1u)) >> 16;
    return (ushort_t)r;
}
__device__ __forceinline__ float bf2f(ushort_t b) {
    union { unsigned u; float f; } v; v.u = ((unsigned)b) << 16; return v.f;
}

// async 16B global -> LDS (dest = wave-uniform base; HW adds lane*16)
__device__ __forceinline__ void gload_lds16(const ushort_t* g, ushort_t* l) {
    __builtin_amdgcn_global_load_lds(
        (const __attribute__((address_space(1))) void*)g,
        (__attribute__((address_space(3))) void*)l, 16, 0, 0);
}

#define VMCNT(n) asm volatile("s_waitcnt vmcnt(" #n ")" ::: "memory")
#define RBAR() __builtin_amdgcn_s_barrier()
#define SCHED0() __builtin_amdgcn_sched_barrier(0)

// ---------------------------------------------------------------------------
// Tiny branch: ktr[b][tap][c] = leaky(kern) * sigmoid-gate (mv folded in).
// ---------------------------------------------------------------------------
__global__ void k_tiny(const float* __restrict__ t, const float* __restrict__ tW1,
                       const float* __restrict__ tW2, const float* __restrict__ kW1,
                       const float* __restrict__ kW2, float* __restrict__ ktr) {
    int b = blockIdx.x;
    int c = threadIdx.x;  // 64
    __shared__ float h1[64], g1[64];
    float ts = t[b];
    h1[c] = lrelu(ts * tW1[c]);
    g1[c] = lrelu(ts * kW1[c]);
    __syncthreads();
    float s = 0.f;
    for (int j = 0; j < 64; ++j) s = fmaf(tW2[c * 64 + j], h1[j], s);
    float mvv = 1.f / (1.f + expf(-s));
    for (int q = 0; q < 9; ++q) {
        float s2 = 0.f;
        for (int j = 0; j < 64; ++j) s2 = fmaf(kW2[(c * 9 + q) * 64 + j], g1[j], s2);
        ktr[b * 576 + q * 64 + c] = lrelu(s2) * mvv;
    }
}

// ---------------------------------------------------------------------------
// Zero row buffer (edge-redirect source for staging).
// ---------------------------------------------------------------------------
__global__ void k_zrow(ushort_t* __restrict__ z) {
    int i = blockIdx.x * 256 + threadIdx.x;  // 2048 threads, 16384 shorts
    *(short8*)(z + (size_t)i * 8) = (short8)0;
}

// ---------------------------------------------------------------------------
// Pack three 64x64x3x3 weight tensors, chunk-major for per-chunk W staging:
// wp[conv][chunk][row 0..17][lane][8], row = t*2+ct
//   = W[co = ct*32+(lane&31)][ci = chunk*16+(lane>>5)*8+j], tap t
// ---------------------------------------------------------------------------
__global__ void k_pack(const float* __restrict__ w1, const float* __restrict__ w2,
                       const float* __restrict__ w3, ushort_t* __restrict__ wp) {
    int idx = blockIdx.x * 256 + threadIdx.x;
    if (idx >= 3 * 36864) return;
    int conv = idx / 36864, r = idx % 36864;
    const float* W = conv == 0 ? w1 : (conv == 1 ? w2 : w3);
    int j = r & 7, lane = (r >> 3) & 63;
    int rr = r >> 9;              // 0..71
    int chunk = rr / 18, row = rr % 18;
    int t = row >> 1, ct = row & 1;
    int co = ct * 32 + (lane & 31);
    int ci = chunk * 16 + (lane >> 5) * 8 + j;
    wp[idx] = f2bf(W[(co * 64 + ci) * 9 + t]);
}

// ---------------------------------------------------------------------------
// Transpose x: fp32 NCHW -> bf16 NHWC (width-256 rows). Block = (b,h).
// ---------------------------------------------------------------------------
__global__ __launch_bounds__(256) void k_tr(const float* __restrict__ x,
                                            ushort_t* __restrict__ xbf) {
    int bid = blockIdx.x;
    int h = bid & 255, b = bid >> 8;
    int t = threadIdx.x;
    for (int it = 0; it < 8; ++it) {
        int idx = t + it * 256;  // (w, g)
        int g = idx & 7, w = idx >> 3;
        const float* src = x + (((size_t)(b * 64 + g * 8) * 256 + h) * 256 + w);
        short8 v;
#pragma unroll
        for (int j = 0; j < 8; ++j) v[j] = (short)f2bf(src[(size_t)j * 65536]);
        *(short8*)(xbf + (((size_t)(b * 256 + h) * 256 + w) * 64 + g * 8)) = v;
    }
}

// ---------------------------------------------------------------------------
// Stage one 16-ci pixel chunk: 3 rows x 258 pix, 7 x gload_lds16 per wave
// (4 waves, stripes of 390 slots). Inverse swizzle in per-lane source addr.
// ---------------------------------------------------------------------------
#define STAGE_X(chunk, xbase)                                                    \
    {                                                                            \
        _Pragma("unroll")                                                        \
        for (int i_ = 0; i_ < 7; ++i_) {                                         \
            int base_ = wv * 390 + i_ * 64;                                      \
            int S_ = base_ + lane;                                               \
            S_ = S_ < CHUNK_SLOTS ? S_ : CHUNK_SLOTS - 1;                        \
            int row_ = (S_ >= 2 * CHUNK_ROW) ? 2 : (S_ >= CHUNK_ROW ? 1 : 0);    \
            int rem_ = S_ - row_ * CHUNK_ROW;                                    \
            int mg_ = rem_ >> 3, sl_ = rem_ & 7;                                 \
            int sp_ = sl_ ^ (mg_ & 7);                                           \
            int p_ = mg_ * 4 + (sp_ >> 1), g_ = sp_ & 1;                         \
            int wsx_ = p_ - 1;                                                   \
            bool edge_ = (unsigned)wsx_ >= 256u;                                 \
            const ushort_t* rp_ = (row_ == 0) ? rb0 : (row_ == 1 ? rb1 : rb2);   \
            const ushort_t* src_ =                                               \
                edge_ ? zv : (rp_ + wsx_ * 64 + (chunk)*16 + g_ * 8);            \
            gload_lds16(src_, xs + (xbase) + (size_t)base_ * 8);                 \
        }                                                                        \
    }

// Stage the 18-row weight slice of one chunk into the single W buffer:
// 5 loads per wave (rows wv*5+i, clamped; rows 18-19 are pad dups).
#define STAGE_W(chunk)                                                           \
    {                                                                            \
        _Pragma("unroll")                                                        \
        for (int i_ = 0; i_ < 5; ++i_) {                                         \
            int row_ = wv * 5 + i_;                                              \
            int rc_ = row_ > 17 ? 17 : row_;                                     \
            gload_lds16(wp + (size_t)((chunk)*18 + rc_) * 512 + lane * 8,        \
                        xs + (size_t)row_ * 512);                                \
        }                                                                        \
    }

// Compute one chunk: A (weights) and B (pixels) both from LDS (lgkmcnt only).
#define COMPUTE(xbase)                                                           \
    {                                                                            \
        __builtin_amdgcn_s_setprio(1);                                           \
        _Pragma("unroll")                                                        \
        for (int t_ = 0; t_ < 9; ++t_) {                                         \
            short8 a0 = *(const short8*)(xs + (size_t)(t_ * 2) * 512 + lane * 8);\
            short8 a1 = *(const short8*)(xs + (size_t)(t_ * 2 + 1) * 512 + lane * 8); \
            const int dwx_ = t_ % 3, rr_ = t_ / 3;                               \
            _Pragma("unroll")                                                    \
            for (int pt_ = 0; pt_ < 2; ++pt_) {                                  \
                int p_ = pw0 + pt_ * 32 + l31 + dwx_;                            \
                int mg_ = p_ >> 2;                                               \
                int sl_ = ((p_ & 3) * 2 + lhi) ^ (mg_ & 7);                      \
                short8 bf = *(const short8*)(                                    \
                    xs + (xbase) + (size_t)(rr_ * CHUNK_ROW + mg_ * 8 + sl_) * 8);\
                acc[0][pt_] = __builtin_amdgcn_mfma_f32_32x32x16_bf16(           \
                    a0, bf, acc[0][pt_], 0, 0, 0);                               \
                acc[1][pt_] = __builtin_amdgcn_mfma_f32_32x32x16_bf16(           \
                    a1, bf, acc[1][pt_], 0, 0, 0);                               \
            }                                                                    \
        }                                                                        \
        __builtin_amdgcn_s_setprio(0);                                           \
    }

// ---------------------------------------------------------------------------
// 3x3 conv 64->64. Block = (b,h) XCD-swizzled, 4 waves, each 64co x 64pix.
// OMODE: 0 = bf16 NHWC + leaky; 1 = bf16 NCHW + leaky; 2 = fp32 NCHW + bias.
// ---------------------------------------------------------------------------
template <int OMODE>
__global__ __launch_bounds__(256, 2) void k_conv(
    const ushort_t* __restrict__ in, const ushort_t* __restrict__ zv,
    const ushort_t* __restrict__ wp, const float* __restrict__ bias,
    void* __restrict__ outp) {
    extern __shared__ __align__(16) ushort_t xs[];  // [W 20r][xb0][xb1]
    const int tid = threadIdx.x;
    const int lane = tid & 63;
    const int wv = tid >> 6;  // 0..3
    const unsigned bid = blockIdx.x;
    const unsigned L = (bid & 7u) * 512u + (bid >> 3);  // 4096 = 8*512 bijective
    const int h = L & 255, b = L >> 8;
    const int l31 = lane & 31, lhi = lane >> 5;
    const int pw0 = wv * 64;

    const ushort_t* rb0 = (h > 0)   ? in + ((size_t)(b * 256 + h - 1)) * 16384 : zv;
    const ushort_t* rb1 =             in + ((size_t)(b * 256 + h)) * 16384;
    const ushort_t* rb2 = (h < 255) ? in + ((size_t)(b * 256 + h + 1)) * 16384 : zv;

    f32x16 acc[2][2];
#pragma unroll
    for (int a = 0; a < 2; ++a)
#pragma unroll
        for (int c = 0; c < 2; ++c) acc[a][c] = (f32x16)0.0f;

    // FIFO per wave: W0(5) X0(7) X1(7) | C0 | W1(5) X2(7) | C1 | W2(5) X3(7)
    //                | C2 | W3(5) | C3.  VMCNT(7) everywhere retires exactly
    //                the W+X needed; final VMCNT(0).
    STAGE_W(0);
    STAGE_X(0, XB0);
    STAGE_X(1, XB1);
    VMCNT(7);   // retire W0+X0 (12 of 19); X1 in flight
    RBAR(); SCHED0();
    COMPUTE(XB0);
    RBAR();     // all waves done reading W0 + xb0
    STAGE_W(1); STAGE_X(2, XB0);
    VMCNT(7);   // retire X1+W1 (12 of 19); X2 in flight
    RBAR(); SCHED0();
    COMPUTE(XB1);
    RBAR();
    STAGE_W(2); STAGE_X(3, XB1);
    VMCNT(7);   // retire X2+W2; X3 in flight
    RBAR(); SCHED0();
    COMPUTE(XB0);
    RBAR();
    STAGE_W(3);
    VMCNT(0);   // retire X3+W3
    RBAR(); SCHED0();
    COMPUTE(XB1);

    // Epilogue. D layout: col(pix)=lane&31, row(co)=(reg&3)+8*(reg>>2)+4*(lane>>5)
    const int co_b = 4 * lhi;
    if (OMODE == 0) {
        ushort_t* outb = (ushort_t*)outp + ((size_t)(b * 256 + h)) * 16384;
#pragma unroll
        for (int ct = 0; ct < 2; ++ct)
#pragma unroll
            for (int pt = 0; pt < 2; ++pt) {
                int pix = pw0 + pt * 32 + l31;
                ushort_t* po = outb + (size_t)pix * 64 + ct * 32 + co_b;
#pragma unroll
                for (int q = 0; q < 4; ++q) {
                    float4v bv = *(const float4v*)(bias + ct * 32 + co_b + 8 * q);
                    short4v sv;
#pragma unroll
                    for (int m = 0; m < 4; ++m) {
                        float v = lrelu(acc[ct][pt][q * 4 + m] + bv[m]);
                        sv[m] = (short)f2bf(v);
                    }
                    *(short4v*)(po + 8 * q) = sv;
                }
            }
    } else if (OMODE == 1) {
        ushort_t* pb = (ushort_t*)outp + (((size_t)b * 64) << 16) + h * 256;
#pragma unroll
        for (int ct = 0; ct < 2; ++ct)
#pragma unroll
            for (int pt = 0; pt < 2; ++pt) {
                int pix = pw0 + pt * 32 + l31;
#pragma unroll
                for (int q = 0; q < 4; ++q) {
                    float4v bv = *(const float4v*)(bias + ct * 32 + co_b + 8 * q);
#pragma unroll
                    for (int m = 0; m < 4; ++m) {
                        int c = ct * 32 + co_b + 8 * q + m;
                        float v = lrelu(acc[ct][pt][q * 4 + m] + bv[m]);
                        pb[((size_t)c << 16) + pix] = f2bf(v);
                    }
                }
            }
    } else {
        float* pb = (float*)outp + (((size_t)b * 64) << 16) + h * 256;
#pragma unroll
        for (int ct = 0; ct < 2; ++ct)
#pragma unroll
            for (int pt = 0; pt < 2; ++pt) {
                int pix = pw0 + pt * 32 + l31;
#pragma unroll
                for (int q = 0; q < 4; ++q) {
                    float4v bv = *(const float4v*)(bias + ct * 32 + co_b + 8 * q);
#pragma unroll
                    for (int m = 0; m < 4; ++m) {
                        int c = ct * 32 + co_b + 8 * q + m;
                        pb[((size_t)c << 16) + pix] = acc[ct][pt][q * 4 + m] + bv[m];
                    }
                }
            }
    }
}

// ---------------------------------------------------------------------------
// Final depthwise: out[b][c][h][w] += sum_tap ktr[b][tap][c] * f2[b][c][h'][w']
// Block = (b, c, 8-row band); f2 is bf16 NCHW. High occupancy, ~roofline.
// ---------------------------------------------------------------------------
__global__ __launch_bounds__(256) void k_fin(const ushort_t* __restrict__ f2,
                                             const float* __restrict__ ktr,
                                             float* __restrict__ out) {
    __shared__ __align__(16) ushort_t s[10 * 272];
    const unsigned bid = blockIdx.x;
    const unsigned L = (bid & 7u) * 4096u + (bid >> 3);  // bijective, 32768=8*4096
    const int hb = L & 31, c = (L >> 5) & 63, b = L >> 11;
    const int h0 = hb * 8;
    const int w = threadIdx.x;

    const ushort_t* f2c = f2 + (((size_t)(b * 64 + c)) << 16);
    for (int i = w; i < 320; i += 256) {
        int r = i >> 5, seg = i & 31;
        int hs = h0 - 1 + r;
        short8 v = (short8)0;
        if ((unsigned)hs < 256u) v = *(const short8*)(f2c + hs * 256 + seg * 8);
        *(short8*)(&s[r * 272 + 8 + seg * 8]) = v;
        if (seg == 0) s[r * 272 + 7] = 0;
        if (seg == 31) s[r * 272 + 264] = 0;
    }
    __syncthreads();

    float kv[9];
#pragma unroll
    for (int t9 = 0; t9 < 9; ++t9) kv[t9] = ktr[b * 576 + t9 * 64 + c];

    float lv[10], cv[10], rv[10];
#pragma unroll
    for (int r = 0; r < 10; ++r) {
        lv[r] = bf2f(s[r * 272 + 7 + w]);
        cv[r] = bf2f(s[r * 272 + 8 + w]);
        rv[r] = bf2f(s[r * 272 + 9 + w]);
    }

    float* ob = out + (((size_t)(b * 64 + c)) << 16) + h0 * 256 + w;
#pragma unroll
    for (int rr = 0; rr < 8; ++rr) {
        float dwv = 0.f;
#pragma unroll
        for (int r3 = 0; r3 < 3; ++r3) {
            dwv = fmaf(kv[r3 * 3 + 0], lv[rr + r3], dwv);
            dwv = fmaf(kv[r3 * 3 + 1], cv[rr + r3], dwv);
            dwv = fmaf(kv[r3 * 3 + 2], rv[rr + r3], dwv);
        }
        float* po = ob + rr * 256;
        *po = *po + dwv;
    }
}

// ---------------------------------------------------------------------------
extern "C" void kernel_launch(void* const* d_in, const int* in_sizes, int n_in,
                              void* d_out, int out_size, void* d_ws, size_t ws_size,
                              hipStream_t stream) {
    const float* x   = (const float*)d_in[0];
    const float* t   = (const float*)d_in[1];
    const float* tW1 = (const float*)d_in[2];
    const float* tW2 = (const float*)d_in[3];
    const float* fW1 = (const float*)d_in[4];
    const float* fb1 = (const float*)d_in[5];
    const float* fW2 = (const float*)d_in[6];
    const float* fb2 = (const float*)d_in[7];
    const float* kW1 = (const float*)d_in[8];
    const float* kW2 = (const float*)d_in[9];
    const float* cW  = (const float*)d_in[10];
    const float* cb  = (const float*)d_in[11];

    // ws: [ktr 36K @0][wp 216K @65536][zv 32K @294912]
    //     [R1 xbf 128MB @512K]  (never overwritten)
    //     [R2 f2 128MB @512K+128MB]
    // f1 (bf16 NHWC) lives in d_out[0..128MB) — dead before conv<2> writes.
    char* ws = (char*)d_ws;
    float*    ktr  = (float*)ws;
    ushort_t* wp   = (ushort_t*)(ws + 65536);
    ushort_t* zv   = (ushort_t*)(ws + 294912);
    ushort_t* xbf  = (ushort_t*)(ws + (512u << 10));                       // R1
    ushort_t* f2n  = (ushort_t*)(ws + (512u << 10) + ((size_t)128 << 20)); // R2
    ushort_t* f1bf = (ushort_t*)d_out;
    float*    out  = (float*)d_out;

    hipFuncSetAttribute(reinterpret_cast<const void*>(&k_conv<0>),
                        hipFuncAttributeMaxDynamicSharedMemorySize, DYN_LDS);
    hipFuncSetAttribute(reinterpret_cast<const void*>(&k_conv<1>),
                        hipFuncAttributeMaxDynamicSharedMemorySize, DYN_LDS);
    hipFuncSetAttribute(reinterpret_cast<const void*>(&k_conv<2>),
                        hipFuncAttributeMaxDynamicSharedMemorySize, DYN_LDS);

    k_tiny<<<dim3(16), dim3(64), 0, stream>>>(t, tW1, tW2, kW1, kW2, ktr);
    k_zrow<<<dim3(8), dim3(256), 0, stream>>>(zv);
    k_pack<<<dim3((3 * 36864 + 255) / 256), dim3(256), 0, stream>>>(fW1, fW2, cW, wp);
    k_tr<<<dim3(4096), dim3(256), 0, stream>>>(x, xbf);

    // conv0: x -> f1 (bf16 NHWC, in d_out); conv1: f1 -> f2 (bf16 NCHW, R2);
    // conv2: x -> d_out (fp32 NCHW, +cb); k_fin: out += dw(f2)*gate.
    k_conv<0><<<dim3(4096), dim3(256), DYN_LDS, stream>>>(xbf, zv, wp, fb1, (void*)f1bf);
    k_conv<1><<<dim3(4096), dim3(256), DYN_LDS, stream>>>(f1bf, zv, wp + 36864, fb2, (void*)f2n);
    k_conv<2><<<dim3(4096), dim3(256), DYN_LDS, stream>>>(xbf, zv, wp + 2 * 36864, cb, (void*)out);
    k_fin<<<dim3(32768), dim3(256), 0, stream>>>(f2n, ktr, out);
}

// Round 16
// 586.718 us; speedup vs baseline: 1.6417x; 1.0394x over previous
//
#include <hip/hip_runtime.h>
#include <cstdint>

// B=16, C=64, H=W=256. 3x3 convs via bf16 MFMA implicit GEMM.
// Round 16: conv0+conv2 merged (same input -> B ds_read feeds 4 MFMAs) on the
// round-15 2-blocks/CU structure: single-buffered pixel chunk (26KB) +
// 36-row merged weight slice (41KB) staged per chunk in one vmcnt FIFO =
// 67KB LDS -> 2 blocks/CU; per-chunk 2-phase drain hidden by the co-resident
// block. conv1 keeps the round-15 kernel (passed, ~150us). k_fin unchanged.
using short8  = __attribute__((ext_vector_type(8))) short;
using short4v = __attribute__((ext_vector_type(4))) short;
using f32x16  = __attribute__((ext_vector_type(16))) float;
using float4v = __attribute__((ext_vector_type(4))) float;
typedef unsigned short ushort_t;

#define CHUNK_ROW 520       // 65 macro-groups x 8 slots (16 ci)
#define CHUNK_SLOTS 1560    // 3 rows
#define BUF_SLOTS 1632      // padded (stage stripes overrun to 1617)
#define XSHW (BUF_SLOTS * 8)   // shorts per pixel buffer = 13056
#define WSHW (20 * 512)        // conv1: weight buffer (18 rows + 2 pad)
#define XB0 WSHW
#define XB1 (WSHW + XSHW)
#define DYN1 ((WSHW + 2 * XSHW) * 2)     // conv1: 72704 B
#define WSHM (40 * 512)        // merged: 36 rows + 4 pad = 20480 shorts
#define XBM WSHM               // merged pixel buffer offset (shorts)
#define DYN02 ((WSHM + XSHW) * 2)        // merged: 67072 B

__device__ __forceinline__ float lrelu(float x) { return x > 0.f ? x : 0.1f * x; }

__device__ __forceinline__ ushort_t f2bf(float f) {
    union { float f; unsigned u; } v; v.f = f;
    unsigned r = (v.u + 0x7FFFu + ((v.u >> 16) & 1u)) >> 16;
    return (ushort_t)r;
}
__device__ __forceinline__ float bf2f(ushort_t b) {
    union { unsigned u; float f; } v; v.u = ((unsigned)b) << 16; return v.f;
}

// async 16B global -> LDS (dest = wave-uniform base; HW adds lane*16)
__device__ __forceinline__ void gload_lds16(const ushort_t* g, ushort_t* l) {
    __builtin_amdgcn_global_load_lds(
        (const __attribute__((address_space(1))) void*)g,
        (__attribute__((address_space(3))) void*)l, 16, 0, 0);
}

#define VMCNT(n) asm volatile("s_waitcnt vmcnt(" #n ")" ::: "memory")
#define RBAR() __builtin_amdgcn_s_barrier()
#define SCHED0() __builtin_amdgcn_sched_barrier(0)

// ---------------------------------------------------------------------------
// Tiny branch: ktr[b][tap][c] = leaky(kern) * sigmoid-gate (mv folded in).
// ---------------------------------------------------------------------------
__global__ void k_tiny(const float* __restrict__ t, const float* __restrict__ tW1,
                       const float* __restrict__ tW2, const float* __restrict__ kW1,
                       const float* __restrict__ kW2, float* __restrict__ ktr) {
    int b = blockIdx.x;
    int c = threadIdx.x;  // 64
    __shared__ float h1[64], g1[64];
    float ts = t[b];
    h1[c] = lrelu(ts * tW1[c]);
    g1[c] = lrelu(ts * kW1[c]);
    __syncthreads();
    float s = 0.f;
    for (int j = 0; j < 64; ++j) s = fmaf(tW2[c * 64 + j], h1[j], s);
    float mvv = 1.f / (1.f + expf(-s));
    for (int q = 0; q < 9; ++q) {
        float s2 = 0.f;
        for (int j = 0; j < 64; ++j) s2 = fmaf(kW2[(c * 9 + q) * 64 + j], g1[j], s2);
        ktr[b * 576 + q * 64 + c] = lrelu(s2) * mvv;
    }
}

// ---------------------------------------------------------------------------
// Zero row buffer (edge-redirect source for staging).
// ---------------------------------------------------------------------------
__global__ void k_zrow(ushort_t* __restrict__ z) {
    int i = blockIdx.x * 256 + threadIdx.x;  // 2048 threads, 16384 shorts
    *(short8*)(z + (size_t)i * 8) = (short8)0;
}

// ---------------------------------------------------------------------------
// Pack weights, chunk-major.
// wpM: [chunk][row 0..35][lane][8]  rows 0-17: fW1, rows 18-35: cW (row=t*2+ct)
// wp2: [chunk][row 0..17][lane][8]  fW2.
//   element = W[co = ct*32+(lane&31)][ci = chunk*16+(lane>>5)*8+j], tap t
// ---------------------------------------------------------------------------
__global__ void k_pack(const float* __restrict__ w1, const float* __restrict__ w2,
                       const float* __restrict__ w3, ushort_t* __restrict__ wpM,
                       ushort_t* __restrict__ wp2) {
    int idx = blockIdx.x * 256 + threadIdx.x;
    const int NM = 4 * 36 * 512;
    if (idx >= NM + 4 * 18 * 512) return;
    const float* W;
    ushort_t* dst;
    int chunk, row, e;
    if (idx < NM) {
        chunk = idx / (36 * 512);
        int rem = idx % (36 * 512);
        row = rem / 512;
        e = rem % 512;
        W = (row < 18) ? w1 : w3;
        dst = wpM + idx;
        row %= 18;
    } else {
        int i2 = idx - NM;
        chunk = i2 / (18 * 512);
        int rem = i2 % (18 * 512);
        row = rem / 512;
        e = rem % 512;
        W = w2;
        dst = wp2 + i2;
    }
    int lane = e >> 3, j = e & 7;
    int t = row >> 1, ct = row & 1;
    int co = ct * 32 + (lane & 31);
    int ci = chunk * 16 + (lane >> 5) * 8 + j;
    *dst = f2bf(W[(co * 64 + ci) * 9 + t]);
}

// ---------------------------------------------------------------------------
// Transpose x: fp32 NCHW -> bf16 NHWC (width-256 rows). Block = (b,h).
// ---------------------------------------------------------------------------
__global__ __launch_bounds__(256) void k_tr(const float* __restrict__ x,
                                            ushort_t* __restrict__ xbf) {
    int bid = blockIdx.x;
    int h = bid & 255, b = bid >> 8;
    int t = threadIdx.x;
    for (int it = 0; it < 8; ++it) {
        int idx = t + it * 256;  // (w, g)
        int g = idx & 7, w = idx >> 3;
        const float* src = x + (((size_t)(b * 64 + g * 8) * 256 + h) * 256 + w);
        short8 v;
#pragma unroll
        for (int j = 0; j < 8; ++j) v[j] = (short)f2bf(src[(size_t)j * 65536]);
        *(short8*)(xbf + (((size_t)(b * 256 + h) * 256 + w) * 64 + g * 8)) = v;
    }
}

// ---------------------------------------------------------------------------
// Stage one 16-ci pixel chunk: 3 rows x 258 pix, 7 x gload_lds16 per wave
// (4 waves, stripes of 390 slots). Inverse swizzle in per-lane source addr.
// ---------------------------------------------------------------------------
#define STAGE_X(chunk, xbase)                                                    \
    {                                                                            \
        _Pragma("unroll")                                                        \
        for (int i_ = 0; i_ < 7; ++i_) {                                         \
            int base_ = wv * 390 + i_ * 64;                                      \
            int S_ = base_ + lane;                                               \
            S_ = S_ < CHUNK_SLOTS ? S_ : CHUNK_SLOTS - 1;                        \
            int row_ = (S_ >= 2 * CHUNK_ROW) ? 2 : (S_ >= CHUNK_ROW ? 1 : 0);    \
            int rem_ = S_ - row_ * CHUNK_ROW;                                    \
            int mg_ = rem_ >> 3, sl_ = rem_ & 7;                                 \
            int sp_ = sl_ ^ (mg_ & 7);                                           \
            int p_ = mg_ * 4 + (sp_ >> 1), g_ = sp_ & 1;                         \
            int wsx_ = p_ - 1;                                                   \
            bool edge_ = (unsigned)wsx_ >= 256u;                                 \
            const ushort_t* rp_ = (row_ == 0) ? rb0 : (row_ == 1 ? rb1 : rb2);   \
            const ushort_t* src_ =                                               \
                edge_ ? zv : (rp_ + wsx_ * 64 + (chunk)*16 + g_ * 8);            \
            gload_lds16(src_, xs + (xbase) + (size_t)base_ * 8);                 \
        }                                                                        \
    }

// conv1: stage 18-row weight slice (5/wave, rows 18-19 pad dups).
#define STAGE_W(chunk)                                                           \
    {                                                                            \
        _Pragma("unroll")                                                        \
        for (int i_ = 0; i_ < 5; ++i_) {                                         \
            int row_ = wv * 5 + i_;                                              \
            int rc_ = row_ > 17 ? 17 : row_;                                     \
            gload_lds16(wp + (size_t)((chunk)*18 + rc_) * 512 + lane * 8,        \
                        xs + (size_t)row_ * 512);                                \
        }                                                                        \
    }

// merged: stage 36-row weight slice (10/wave, rows 36-39 pad dups).
#define STAGE_WM(chunk)                                                          \
    {                                                                            \
        _Pragma("unroll")                                                        \
        for (int i_ = 0; i_ < 10; ++i_) {                                        \
            int row_ = wv * 10 + i_;                                             \
            int rc_ = row_ > 35 ? 35 : row_;                                     \
            gload_lds16(wpM + (size_t)((chunk)*36 + rc_) * 512 + lane * 8,       \
                        xs + (size_t)row_ * 512);                                \
        }                                                                        \
    }

// conv1 compute: A rows 0..17, B from xbase. Pure-LDS cluster.
#define COMPUTE(xbase)                                                           \
    {                                                                            \
        __builtin_amdgcn_s_setprio(1);                                           \
        _Pragma("unroll")                                                        \
        for (int t_ = 0; t_ < 9; ++t_) {                                         \
            short8 a0 = *(const short8*)(xs + (size_t)(t_ * 2) * 512 + lane * 8);\
            short8 a1 = *(const short8*)(xs + (size_t)(t_ * 2 + 1) * 512 + lane * 8); \
            const int dwx_ = t_ % 3, rr_ = t_ / 3;                               \
            _Pragma("unroll")                                                    \
            for (int pt_ = 0; pt_ < 2; ++pt_) {                                  \
                int p_ = pw0 + pt_ * 32 + l31 + dwx_;                            \
                int mg_ = p_ >> 2;                                               \
                int sl_ = ((p_ & 3) * 2 + lhi) ^ (mg_ & 7);                      \
                short8 bf = *(const short8*)(                                    \
                    xs + (xbase) + (size_t)(rr_ * CHUNK_ROW + mg_ * 8 + sl_) * 8);\
                acc[0][pt_] = __builtin_amdgcn_mfma_f32_32x32x16_bf16(           \
                    a0, bf, acc[0][pt_], 0, 0, 0);                               \
                acc[1][pt_] = __builtin_amdgcn_mfma_f32_32x32x16_bf16(           \
                    a1, bf, acc[1][pt_], 0, 0, 0);                               \
            }                                                                    \
        }                                                                        \
        __builtin_amdgcn_s_setprio(0);                                           \
    }

// merged compute: A rows 0..17 (fW1) + 18..35 (cW); one B read -> 4 MFMAs.
#define COMPUTE_M()                                                              \
    {                                                                            \
        __builtin_amdgcn_s_setprio(1);                                           \
        _Pragma("unroll")                                                        \
        for (int t_ = 0; t_ < 9; ++t_) {                                         \
            short8 a0 = *(const short8*)(xs + (size_t)(t_ * 2) * 512 + lane * 8);\
            short8 a1 = *(const short8*)(xs + (size_t)(t_ * 2 + 1) * 512 + lane * 8); \
            short8 c0 = *(const short8*)(xs + (size_t)(18 + t_ * 2) * 512 + lane * 8); \
            short8 c1 = *(const short8*)(xs + (size_t)(19 + t_ * 2) * 512 + lane * 8); \
            const int dwx_ = t_ % 3, rr_ = t_ / 3;                               \
            _Pragma("unroll")                                                    \
            for (int pt_ = 0; pt_ < 2; ++pt_) {                                  \
                int p_ = pw0 + pt_ * 32 + l31 + dwx_;                            \
                int mg_ = p_ >> 2;                                               \
                int sl_ = ((p_ & 3) * 2 + lhi) ^ (mg_ & 7);                      \
                short8 bf = *(const short8*)(                                    \
                    xs + XBM + (size_t)(rr_ * CHUNK_ROW + mg_ * 8 + sl_) * 8);   \
                accA[0][pt_] = __builtin_amdgcn_mfma_f32_32x32x16_bf16(          \
                    a0, bf, accA[0][pt_], 0, 0, 0);                              \
                accA[1][pt_] = __builtin_amdgcn_mfma_f32_32x32x16_bf16(          \
                    a1, bf, accA[1][pt_], 0, 0, 0);                              \
                accC[0][pt_] = __builtin_amdgcn_mfma_f32_32x32x16_bf16(          \
                    c0, bf, accC[0][pt_], 0, 0, 0);                              \
                accC[1][pt_] = __builtin_amdgcn_mfma_f32_32x32x16_bf16(          \
                    c1, bf, accC[1][pt_], 0, 0, 0);                              \
            }                                                                    \
        }                                                                        \
        __builtin_amdgcn_s_setprio(0);                                           \
    }

// ---------------------------------------------------------------------------
// Merged conv0+conv2. Block = (b,h) XCD-swizzled, 4 waves, 64co x 64pix each.
// accA: fW1+fb1+leaky -> f1 bf16 NHWC. accC: cW+cb -> fp32 NCHW (d_out).
// Single pixel buffer; W+X staged per chunk in one FIFO; vmcnt(0) 2-phase;
// 67KB LDS -> 2 blocks/CU hide each other's drains.
// ---------------------------------------------------------------------------
__global__ __launch_bounds__(256, 2) void k_conv02(
    const ushort_t* __restrict__ in, const ushort_t* __restrict__ zv,
    const ushort_t* __restrict__ wpM, const float* __restrict__ ba,
    const float* __restrict__ bc, ushort_t* __restrict__ f1out,
    float* __restrict__ cres) {
    extern __shared__ __align__(16) ushort_t xs[];  // [W 40 rows][X 1632 slots]
    const int tid = threadIdx.x;
    const int lane = tid & 63;
    const int wv = tid >> 6;  // 0..3
    const unsigned bid = blockIdx.x;
    const unsigned L = (bid & 7u) * 512u + (bid >> 3);  // 4096 = 8*512 bijective
    const int h = L & 255, b = L >> 8;
    const int l31 = lane & 31, lhi = lane >> 5;
    const int pw0 = wv * 64;

    const ushort_t* rb0 = (h > 0)   ? in + ((size_t)(b * 256 + h - 1)) * 16384 : zv;
    const ushort_t* rb1 =             in + ((size_t)(b * 256 + h)) * 16384;
    const ushort_t* rb2 = (h < 255) ? in + ((size_t)(b * 256 + h + 1)) * 16384 : zv;

    f32x16 accA[2][2], accC[2][2];
#pragma unroll
    for (int a = 0; a < 2; ++a)
#pragma unroll
        for (int c = 0; c < 2; ++c) { accA[a][c] = (f32x16)0.0f; accC[a][c] = (f32x16)0.0f; }

#pragma unroll
    for (int ch = 0; ch < 4; ++ch) {
        STAGE_WM(ch);
        STAGE_X(ch, XBM);
        VMCNT(0);
        RBAR(); SCHED0();
        COMPUTE_M();
        RBAR();  // protect W+X before next chunk's staging
    }

    // Epilogues. D layout: col(pix)=lane&31, row(co)=(reg&3)+8*(reg>>2)+4*(lane>>5)
    const int co_b = 4 * lhi;
    {   // conv0 -> f1 bf16 NHWC + leaky
        ushort_t* outb = f1out + ((size_t)(b * 256 + h)) * 16384;
#pragma unroll
        for (int ct = 0; ct < 2; ++ct)
#pragma unroll
            for (int pt = 0; pt < 2; ++pt) {
                int pix = pw0 + pt * 32 + l31;
                ushort_t* po = outb + (size_t)pix * 64 + ct * 32 + co_b;
#pragma unroll
                for (int q = 0; q < 4; ++q) {
                    float4v bv = *(const float4v*)(ba + ct * 32 + co_b + 8 * q);
                    short4v sv;
#pragma unroll
                    for (int m = 0; m < 4; ++m) {
                        float v = lrelu(accA[ct][pt][q * 4 + m] + bv[m]);
                        sv[m] = (short)f2bf(v);
                    }
                    *(short4v*)(po + 8 * q) = sv;
                }
            }
    }
    {   // conv2 -> d_out fp32 NCHW + cb
        float* pb = cres + (((size_t)b * 64) << 16) + h * 256;
#pragma unroll
        for (int ct = 0; ct < 2; ++ct)
#pragma unroll
            for (int pt = 0; pt < 2; ++pt) {
                int pix = pw0 + pt * 32 + l31;
#pragma unroll
                for (int q = 0; q < 4; ++q) {
                    float4v bv = *(const float4v*)(bc + ct * 32 + co_b + 8 * q);
#pragma unroll
                    for (int m = 0; m < 4; ++m) {
                        int c = ct * 32 + co_b + 8 * q + m;
                        pb[((size_t)c << 16) + pix] = accC[ct][pt][q * 4 + m] + bv[m];
                    }
                }
            }
    }
}

// ---------------------------------------------------------------------------
// conv1 (round-15 kernel, verbatim): bf16 NHWC in -> leaky -> bf16 NCHW out.
// ---------------------------------------------------------------------------
__global__ __launch_bounds__(256, 2) void k_conv1(
    const ushort_t* __restrict__ in, const ushort_t* __restrict__ zv,
    const ushort_t* __restrict__ wp, const float* __restrict__ bias,
    ushort_t* __restrict__ outp) {
    extern __shared__ __align__(16) ushort_t xs[];  // [W 20r][xb0][xb1]
    const int tid = threadIdx.x;
    const int lane = tid & 63;
    const int wv = tid >> 6;  // 0..3
    const unsigned bid = blockIdx.x;
    const unsigned L = (bid & 7u) * 512u + (bid >> 3);
    const int h = L & 255, b = L >> 8;
    const int l31 = lane & 31, lhi = lane >> 5;
    const int pw0 = wv * 64;

    const ushort_t* rb0 = (h > 0)   ? in + ((size_t)(b * 256 + h - 1)) * 16384 : zv;
    const ushort_t* rb1 =             in + ((size_t)(b * 256 + h)) * 16384;
    const ushort_t* rb2 = (h < 255) ? in + ((size_t)(b * 256 + h + 1)) * 16384 : zv;

    f32x16 acc[2][2];
#pragma unroll
    for (int a = 0; a < 2; ++a)
#pragma unroll
        for (int c = 0; c < 2; ++c) acc[a][c] = (f32x16)0.0f;

    STAGE_W(0);
    STAGE_X(0, XB0);
    STAGE_X(1, XB1);
    VMCNT(7);   // retire W0+X0; X1 in flight
    RBAR(); SCHED0();
    COMPUTE(XB0);
    RBAR();
    STAGE_W(1); STAGE_X(2, XB0);
    VMCNT(7);
    RBAR(); SCHED0();
    COMPUTE(XB1);
    RBAR();
    STAGE_W(2); STAGE_X(3, XB1);
    VMCNT(7);
    RBAR(); SCHED0();
    COMPUTE(XB0);
    RBAR();
    STAGE_W(3);
    VMCNT(0);
    RBAR(); SCHED0();
    COMPUTE(XB1);

    const int co_b = 4 * lhi;
    // bf16 NCHW + leaky
    ushort_t* pb = outp + (((size_t)b * 64) << 16) + h * 256;
#pragma unroll
    for (int ct = 0; ct < 2; ++ct)
#pragma unroll
        for (int pt = 0; pt < 2; ++pt) {
            int pix = pw0 + pt * 32 + l31;
#pragma unroll
            for (int q = 0; q < 4; ++q) {
                float4v bv = *(const float4v*)(bias + ct * 32 + co_b + 8 * q);
#pragma unroll
                for (int m = 0; m < 4; ++m) {
                    int c = ct * 32 + co_b + 8 * q + m;
                    float v = lrelu(acc[ct][pt][q * 4 + m] + bv[m]);
                    pb[((size_t)c << 16) + pix] = f2bf(v);
                }
            }
        }
}

// ---------------------------------------------------------------------------
// Final depthwise: out[b][c][h][w] += sum_tap ktr[b][tap][c] * f2[b][c][h'][w']
// Block = (b, c, 8-row band); f2 is bf16 NCHW. High occupancy, ~roofline.
// ---------------------------------------------------------------------------
__global__ __launch_bounds__(256) void k_fin(const ushort_t* __restrict__ f2,
                                             const float* __restrict__ ktr,
                                             float* __restrict__ out) {
    __shared__ __align__(16) ushort_t s[10 * 272];
    const unsigned bid = blockIdx.x;
    const unsigned L = (bid & 7u) * 4096u + (bid >> 3);  // bijective, 32768=8*4096
    const int hb = L & 31, c = (L >> 5) & 63, b = L >> 11;
    const int h0 = hb * 8;
    const int w = threadIdx.x;

    const ushort_t* f2c = f2 + (((size_t)(b * 64 + c)) << 16);
    for (int i = w; i < 320; i += 256) {
        int r = i >> 5, seg = i & 31;
        int hs = h0 - 1 + r;
        short8 v = (short8)0;
        if ((unsigned)hs < 256u) v = *(const short8*)(f2c + hs * 256 + seg * 8);
        *(short8*)(&s[r * 272 + 8 + seg * 8]) = v;
        if (seg == 0) s[r * 272 + 7] = 0;
        if (seg == 31) s[r * 272 + 264] = 0;
    }
    __syncthreads();

    float kv[9];
#pragma unroll
    for (int t9 = 0; t9 < 9; ++t9) kv[t9] = ktr[b * 576 + t9 * 64 + c];

    float lv[10], cv[10], rv[10];
#pragma unroll
    for (int r = 0; r < 10; ++r) {
        lv[r] = bf2f(s[r * 272 + 7 + w]);
        cv[r] = bf2f(s[r * 272 + 8 + w]);
        rv[r] = bf2f(s[r * 272 + 9 + w]);
    }

    float* ob = out + (((size_t)(b * 64 + c)) << 16) + h0 * 256 + w;
#pragma unroll
    for (int rr = 0; rr < 8; ++rr) {
        float dwv = 0.f;
#pragma unroll
        for (int r3 = 0; r3 < 3; ++r3) {
            dwv = fmaf(kv[r3 * 3 + 0], lv[rr + r3], dwv);
            dwv = fmaf(kv[r3 * 3 + 1], cv[rr + r3], dwv);
            dwv = fmaf(kv[r3 * 3 + 2], rv[rr + r3], dwv);
        }
        float* po = ob + rr * 256;
        *po = *po + dwv;
    }
}

// ---------------------------------------------------------------------------
extern "C" void kernel_launch(void* const* d_in, const int* in_sizes, int n_in,
                              void* d_out, int out_size, void* d_ws, size_t ws_size,
                              hipStream_t stream) {
    const float* x   = (const float*)d_in[0];
    const float* t   = (const float*)d_in[1];
    const float* tW1 = (const float*)d_in[2];
    const float* tW2 = (const float*)d_in[3];
    const float* fW1 = (const float*)d_in[4];
    const float* fb1 = (const float*)d_in[5];
    const float* fW2 = (const float*)d_in[6];
    const float* fb2 = (const float*)d_in[7];
    const float* kW1 = (const float*)d_in[8];
    const float* kW2 = (const float*)d_in[9];
    const float* cW  = (const float*)d_in[10];
    const float* cb  = (const float*)d_in[11];

    // ws: [ktr 36K @0][wpM 144K @65536][wp2 72K @212992][zv 32K @294912]
    //     [R1 128MB @512K]: xbf (until conv02 done), then f2
    //     [R2 128MB @512K+128MB]: f1
    char* ws = (char*)d_ws;
    float*    ktr  = (float*)ws;
    ushort_t* wpM  = (ushort_t*)(ws + 65536);
    ushort_t* wp2  = wpM + 4 * 36 * 512;
    ushort_t* zv   = (ushort_t*)(ws + 294912);
    ushort_t* xbf  = (ushort_t*)(ws + (512u << 10));                       // R1
    ushort_t* f1bf = (ushort_t*)(ws + (512u << 10) + ((size_t)128 << 20)); // R2
    ushort_t* f2n  = xbf;  // R1 reused: xbf dead after k_conv02
    float*    out  = (float*)d_out;

    hipFuncSetAttribute(reinterpret_cast<const void*>(&k_conv02),
                        hipFuncAttributeMaxDynamicSharedMemorySize, DYN02);
    hipFuncSetAttribute(reinterpret_cast<const void*>(&k_conv1),
                        hipFuncAttributeMaxDynamicSharedMemorySize, DYN1);

    k_tiny<<<dim3(16), dim3(64), 0, stream>>>(t, tW1, tW2, kW1, kW2, ktr);
    k_zrow<<<dim3(8), dim3(256), 0, stream>>>(zv);
    k_pack<<<dim3((4 * 36 * 512 + 4 * 18 * 512 + 255) / 256), dim3(256), 0, stream>>>(
        fW1, fW2, cW, wpM, wp2);
    k_tr<<<dim3(4096), dim3(256), 0, stream>>>(x, xbf);

    // conv02: x -> f1 (bf16 NHWC, R2) + d_out (fp32 NCHW, +cb);
    // conv1: f1 -> f2 (bf16 NCHW, R1); k_fin: out += dw(f2)*gate.
    k_conv02<<<dim3(4096), dim3(256), DYN02, stream>>>(
        xbf, zv, wpM, fb1, cb, f1bf, out);
    k_conv1<<<dim3(4096), dim3(256), DYN1, stream>>>(f1bf, zv, wp2, fb2, f2n);
    k_fin<<<dim3(32768), dim3(256), 0, stream>>>(f2n, ktr, out);
}